// Round 13
// baseline (703.531 us; speedup 1.0000x reference)
//
#include <hip/hip_runtime.h>

#define B_   4
#define CIN  64
#define COUT 64
#define H_   128
#define W_   128
#define HW   (H_*W_)
#define KK   9
#define HALO 3
#define TI   4
#define TJ   16
#define ROWS_R (TI + 2*HALO)            // 10
#define COLS_R (TJ + 2*HALO)            // 22
#define RECS   (ROWS_R * COLS_R)        // 220
#define OFFB   (RECS * 128)             // 28160
#define SMEMB  (OFFB + 27 * TI * TJ * 4) // 35072
#define NBLK   1024                     // 4 b x 32 ti x 8 tj
#define REP    4

typedef short bf16x8 __attribute__((ext_vector_type(8)));
typedef float f32x4  __attribute__((ext_vector_type(4)));
typedef float f32x2  __attribute__((ext_vector_type(2)));
typedef unsigned int u32;
typedef unsigned int u32x4 __attribute__((ext_vector_type(4)));

__device__ __forceinline__ unsigned short f2bf(float f) {
    unsigned int u = __float_as_uint(f);
    u = (u + 0x7FFFu + ((u >> 16) & 1u)) >> 16;
    return (unsigned short)u;
}

// ---- Kernel 1: x (B,CIN,H,W) f32 -> xt (B,H,W,CIN) bf16 ----
__global__ __launch_bounds__(256) void k_transpose(const float* __restrict__ x,
                                                   unsigned short* __restrict__ xt) {
    __shared__ float lds[64 * 129];
    int bi = blockIdx.x;
    int b = bi >> 7, i = bi & 127;
    int tid = threadIdx.x;
#pragma unroll
    for (int cc = 0; cc < 32; ++cc) {
        int c = cc * 2 + (tid >> 7);
        int w = tid & 127;
        lds[c * 129 + w] = x[((b * CIN + c) * H_ + i) * W_ + w];
    }
    __syncthreads();
#pragma unroll
    for (int q = 0; q < 32; ++q) {
        int c = tid & 63;
        int w = q * 4 + (tid >> 6);
        xt[((b * H_ + i) * W_ + w) * CIN + c] = f2bf(lds[c * 129 + w]);
    }
}

// ---- Kernel 2: weight -> MFMA B-fragment order (bf16) ----
__global__ __launch_bounds__(256) void k_weight(const float* __restrict__ w,
                                                unsigned short* __restrict__ wtf) {
    int t = blockIdx.x * 256 + threadIdx.x;
    if (t >= 18 * 4 * 64 * 8) return;
    int j    = t & 7;
    int lane = (t >> 3) & 63;
    int nt   = (t >> 9) & 3;
    int s    = t >> 11;
    int kg   = s * 32 + ((lane >> 4) << 3) + j;
    int n    = nt * 16 + (lane & 15);
    int kpos = kg >> 6, c = kg & 63;
    wtf[t] = f2bf(w[(n * CIN + c) * 9 + kpos]);
}

// ---- Main (R8 structure), templated ablation:
//   VAR=0 stage only | VAR=1 +meta/gather/blend | VAR=2 +B+MFMA | VAR=3 full
template<int VAR>
__global__ __launch_bounds__(512, 6) void k_main_t(
    const unsigned short* __restrict__ xt,
    const float* __restrict__ offset,
    const float* __restrict__ mask,
    const unsigned short* __restrict__ wtf,
    const float* __restrict__ bias,
    float* __restrict__ out) {
    __shared__ __align__(16) unsigned char smem[SMEMB];   // 34.25 KB

    const int tid  = threadIdx.x;
    const int lane = tid & 63;
    const int wv   = tid >> 6;          // 0..7
    const int wvl  = wv & 3;            // px row within tile
    const int half = wv >> 2;           // K-half
    const int T  = ((blockIdx.x & 7) << 7) + (blockIdx.x >> 3);
    const int b  = T >> 8;
    const int i0 = ((T >> 3) & 31) * TI;
    const int j0 = (T & 7) * TJ;
    const char* xb = (const char*)xt + (size_t)b * HW * 128;

    const int p  = lane & 15;            // px col
    const int g  = lane >> 4;            // channel group
    const int ir = i0 + wvl;
    const int jc = j0 + p;
    const float* offl = (const float*)(smem + OFFB) + wvl * 16 + p;
    const bf16x8* wp = (const bf16x8*)wtf;

    for (int rep = 0; rep < REP; ++rep) {
    // -------- stage 10x22 record region, chunk-rotation swizzle --------
    {
        const int iA = i0 - HALO, jA = j0 - HALO;
#pragma unroll
        for (int k = 0; k < 4; ++k) {
            int idx = k * 512 + tid;          // 1760 chunks
            if (idx < RECS * 8) {
                int rec = idx >> 3, c = idx & 7;
                int rr = rec / COLS_R, cc = rec - rr * COLS_R;
                int gr = min(max(iA + rr, 0), H_ - 1);
                int gc = min(max(jA + cc, 0), W_ - 1);
                u32x4 v = *(const u32x4*)(xb + (((gr << 7) + gc) << 7) + (c << 4));
                *(u32x4*)(smem + (rec << 7) + (((c + rec) & 7) << 4)) = v;
            }
        }
    }
    // -------- stage offset+mask planes [27][4][16] f32 --------
    {
        const float* op = offset + (size_t)b * 18 * HW;
        const float* mp = mask   + (size_t)b * 9  * HW;
        if (tid < 432) {
            int q = tid >> 4, rem = tid & 15;
            int row = rem >> 2, c4 = (rem & 3) << 2;
            const float* src = (q < 18 ? op + q * HW : mp + (q - 18) * HW)
                               + (i0 + row) * W_ + j0 + c4;
            *(f32x4*)(smem + OFFB + tid * 16) = *(const f32x4*)src;
        }
    }
    __syncthreads();

    if constexpr (VAR == 0) {
        // keep staged data live, measure staging cost only
        float t0 = *(const volatile float*)(smem + (tid << 2));
        float t1 = *(const volatile float*)(smem + OFFB + ((tid & 255) << 2));
        asm volatile("" :: "v"(t0), "v"(t1));
        __syncthreads();
        continue;
    }

    f32x4 acc0 = {0,0,0,0}, acc1 = {0,0,0,0}, acc2 = {0,0,0,0}, acc3 = {0,0,0,0};

#define KP_BODY(KP, H0, H1) do { \
    float oi  = offl[(2*(KP)) * 64]; \
    float oj  = offl[(2*(KP)+1) * 64]; \
    float msk = offl[(18+(KP)) * 64]; \
    float ci = oi + (float)(ir + (KP)/3 - 1); \
    float cj = oj + (float)(jc + (KP)%3 - 1); \
    float fli = floorf(ci), flj = floorf(cj); \
    float fi = ci - fli, fj = cj - flj; \
    int li = (int)fli, lj = (int)flj; \
    int rli = li - (i0 - HALO), rlj = lj - (j0 - HALO); \
    bool inr = ((unsigned)rli <= (unsigned)(ROWS_R-2)) && \
               ((unsigned)rlj <= (unsigned)(COLS_R-2)); \
    float vy0 = (li   >= 0 && li   < H_) ? 1.f : 0.f; \
    float vy1 = (li+1 >= 0 && li+1 < H_) ? 1.f : 0.f; \
    float vx0 = (lj   >= 0 && lj   < W_) ? 1.f : 0.f; \
    float vx1 = (lj+1 >= 0 && lj+1 < W_) ? 1.f : 0.f; \
    float gi = fi * msk, gj = fj * msk; \
    float w11 = gi * fj; \
    float w4x = (msk - gi - gj + w11) * vy0 * vx0; \
    float w4y = (gj - w11) * vy0 * vx1; \
    float w4z = (gi - w11) * vy1 * vx0; \
    float w4w = w11 * vy1 * vx1; \
    int y0 = min(max(li,   0), H_-1), y1 = min(max(li+1, 0), H_-1); \
    int x0 = min(max(lj,   0), W_-1), x1 = min(max(lj+1, 0), W_-1); \
    int a00 = ((y0 << 7) + x0) << 7, a01 = ((y0 << 7) + x1) << 7; \
    int a10 = ((y1 << 7) + x0) << 7, a11 = ((y1 << 7) + x1) << 7; \
    int rli_c = min(max(rli, 0), ROWS_R-2), rlj_c = min(max(rlj, 0), COLS_R-2); \
    int r00 = rli_c * COLS_R + rlj_c; \
    int r01 = r00 + 1, r10 = r00 + COLS_R, r11 = r00 + COLS_R + 1; \
    f32x2 wx = {w4x, w4x}, wy = {w4y, w4y}, wz = {w4z, w4z}, ww = {w4w, w4w}; \
    _Pragma("unroll") \
    for (int h = (H0); h < (H1); ++h) { \
        int ch = h * 4 + g; \
        u32x4 q00 = *(const u32x4*)(smem + (r00 << 7) + (((ch + r00) & 7) << 4)); \
        u32x4 q01 = *(const u32x4*)(smem + (r01 << 7) + (((ch + r01) & 7) << 4)); \
        u32x4 q10 = *(const u32x4*)(smem + (r10 << 7) + (((ch + r10) & 7) << 4)); \
        u32x4 q11 = *(const u32x4*)(smem + (r11 << 7) + (((ch + r11) & 7) << 4)); \
        if (!inr) { \
            int c = (g << 4) + (h << 6); \
            q00 = *(const u32x4*)(xb + a00 + c); \
            q01 = *(const u32x4*)(xb + a01 + c); \
            q10 = *(const u32x4*)(xb + a10 + c); \
            q11 = *(const u32x4*)(xb + a11 + c); \
        } \
        u32x4 po; \
        _Pragma("unroll") \
        for (int q = 0; q < 4; ++q) { \
            f32x2 c00 = {__uint_as_float(q00[q] << 16), __uint_as_float(q00[q] & 0xFFFF0000u)}; \
            f32x2 c01 = {__uint_as_float(q01[q] << 16), __uint_as_float(q01[q] & 0xFFFF0000u)}; \
            f32x2 c10 = {__uint_as_float(q10[q] << 16), __uint_as_float(q10[q] & 0xFFFF0000u)}; \
            f32x2 c11 = {__uint_as_float(q11[q] << 16), __uint_as_float(q11[q] & 0xFFFF0000u)}; \
            f32x2 r = wx * c00 + wy * c01 + wz * c10 + ww * c11; \
            po[q] = __builtin_amdgcn_perm(__float_as_uint(r.y) + 0x8000u, \
                                          __float_as_uint(r.x) + 0x8000u, 0x07060302u); \
        } \
        if constexpr (VAR == 1) { \
            asm volatile("" :: "v"(po[0]), "v"(po[1]), "v"(po[2]), "v"(po[3])); \
        } else { \
            bf16x8 af; *(u32x4*)&af = po; \
            int s = (KP) * 2 + h; \
            acc0 = __builtin_amdgcn_mfma_f32_16x16x32_bf16(af, wp[(s*4+0)*64 + lane], acc0, 0, 0, 0); \
            acc1 = __builtin_amdgcn_mfma_f32_16x16x32_bf16(af, wp[(s*4+1)*64 + lane], acc1, 0, 0, 0); \
            acc2 = __builtin_amdgcn_mfma_f32_16x16x32_bf16(af, wp[(s*4+2)*64 + lane], acc2, 0, 0, 0); \
            acc3 = __builtin_amdgcn_mfma_f32_16x16x32_bf16(af, wp[(s*4+3)*64 + lane], acc3, 0, 0, 0); \
        } \
    } } while (0)

    if (!half) {
        KP_BODY(0, 0, 2); KP_BODY(1, 0, 2); KP_BODY(2, 0, 2);
        KP_BODY(3, 0, 2); KP_BODY(8, 0, 1);
    } else {
        KP_BODY(4, 0, 2); KP_BODY(5, 0, 2); KP_BODY(6, 0, 2);
        KP_BODY(7, 0, 2); KP_BODY(8, 1, 2);
    }

    if constexpr (VAR == 1) { __syncthreads(); continue; }

    // -------- epilogue --------
    __syncthreads();
    f32x4* dump = (f32x4*)smem;                  // [nt][4 rows][64 lanes]
    if constexpr (VAR == 2) {
        dump[(0*4 + wvl)*64 + lane] = acc0;
        dump[(1*4 + wvl)*64 + lane] = acc1;
        dump[(2*4 + wvl)*64 + lane] = acc2;
        dump[(3*4 + wvl)*64 + lane] = acc3;
        __syncthreads();
        continue;
    }

    if (half) {
        dump[(0*4 + wvl)*64 + lane] = acc0;
        dump[(1*4 + wvl)*64 + lane] = acc1;
        dump[(2*4 + wvl)*64 + lane] = acc2;
        dump[(3*4 + wvl)*64 + lane] = acc3;
    }
    __syncthreads();
    if (!half) {
        acc0 += dump[(0*4 + wvl)*64 + lane];
        acc1 += dump[(1*4 + wvl)*64 + lane];
        acc2 += dump[(2*4 + wvl)*64 + lane];
        acc3 += dump[(3*4 + wvl)*64 + lane];
        float bs0 = bias[p], bs1 = bias[16 + p], bs2 = bias[32 + p], bs3 = bias[48 + p];
#pragma unroll
        for (int r = 0; r < 4; ++r) { acc0[r] += bs0; acc1[r] += bs1; acc2[r] += bs2; acc3[r] += bs3; }
    }
    __syncthreads();
    float* cst = (float*)smem;                   // [64 cout][68 px]
    if (!half) {
        const int pm = wvl * 16 + (g << 2);
        *(f32x4*)&cst[(p)      * 68 + pm] = acc0;
        *(f32x4*)&cst[(16 + p) * 68 + pm] = acc1;
        *(f32x4*)&cst[(32 + p) * 68 + pm] = acc2;
        *(f32x4*)&cst[(48 + p) * 68 + pm] = acc3;
    }
    __syncthreads();
    const size_t obase = (size_t)b * (COUT * HW) + i0 * W_ + j0;
#pragma unroll
    for (int k = 0; k < 2; ++k) {
        int idx = k * 512 + tid;                 // 1024 f32x4 chunks
        int cout = idx >> 4, chunk = idx & 15;
        int row = chunk >> 2, cq = (chunk & 3) << 2;
        f32x4 vv = *(const f32x4*)&cst[cout * 68 + chunk * 4];
        __builtin_nontemporal_store(vv,
            (f32x4*)&out[obase + (size_t)cout * HW + row * W_ + cq]);
    }
    __syncthreads();
    } // rep
#undef KP_BODY
}

extern "C" void kernel_launch(void* const* d_in, const int* in_sizes, int n_in,
                              void* d_out, int out_size, void* d_ws, size_t ws_size,
                              hipStream_t stream) {
    const float* x      = (const float*)d_in[0];
    const float* offset = (const float*)d_in[1];
    const float* mask   = (const float*)d_in[2];
    const float* weight = (const float*)d_in[3];
    const float* bias   = (const float*)d_in[4];
    float* out = (float*)d_out;
    char* ws = (char*)d_ws;
    unsigned short* xt  = (unsigned short*)ws;                        // 8 MB
    unsigned short* wtf = (unsigned short*)(ws + 8388608);            // 72 KB

    k_transpose<<<B_ * H_, 256, 0, stream>>>(x, xt);
    k_weight<<<144, 256, 0, stream>>>(weight, wtf);
    k_main_t<0><<<NBLK, 512, 0, stream>>>(xt, offset, mask, wtf, bias, out);
    k_main_t<1><<<NBLK, 512, 0, stream>>>(xt, offset, mask, wtf, bias, out);
    k_main_t<2><<<NBLK, 512, 0, stream>>>(xt, offset, mask, wtf, bias, out);
    k_main_t<3><<<NBLK, 512, 0, stream>>>(xt, offset, mask, wtf, bias, out);
}

// Round 15
// 39.740 us; speedup vs baseline: 17.7033x; 17.7033x over previous
//
#include <hip/hip_runtime.h>

#define B_   4
#define CIN  64
#define COUT 64
#define H_   128
#define W_   128
#define HW   (H_*W_)
#define KK   9
#define HALO 3
#define ROWS_R (8 + 2*HALO)    // 14
#define COLS_R (16 + 2*HALO)   // 22
#define RECS   (ROWS_R * COLS_R)        // 308
#define OFFB   (RECS * 128)             // 39424
#define SMEMB  (OFFB + 27 * 128 * 4)    // 53248
#define NBLK 512           // 4 b x 16 ti x 8 tj

typedef short bf16x8 __attribute__((ext_vector_type(8)));
typedef float f32x4  __attribute__((ext_vector_type(4)));
typedef float f32x2  __attribute__((ext_vector_type(2)));
typedef unsigned int u32;
typedef unsigned int u32x4 __attribute__((ext_vector_type(4)));

__device__ __forceinline__ unsigned short f2bf(float f) {
    unsigned int u = __float_as_uint(f);
    u = (u + 0x7FFFu + ((u >> 16) & 1u)) >> 16;
    return (unsigned short)u;
}

// ---- Kernel 1: x (B,CIN,H,W) f32 -> xt (B,H,W,CIN) bf16 ----
__global__ __launch_bounds__(256) void k_transpose(const float* __restrict__ x,
                                                   unsigned short* __restrict__ xt) {
    __shared__ float lds[64 * 129];
    int bi = blockIdx.x;
    int b = bi >> 7, i = bi & 127;
    int tid = threadIdx.x;
#pragma unroll
    for (int cc = 0; cc < 32; ++cc) {
        int c = cc * 2 + (tid >> 7);
        int w = tid & 127;
        lds[c * 129 + w] = x[((b * CIN + c) * H_ + i) * W_ + w];
    }
    __syncthreads();
#pragma unroll
    for (int q = 0; q < 32; ++q) {
        int c = tid & 63;
        int w = q * 4 + (tid >> 6);
        xt[((b * H_ + i) * W_ + w) * CIN + c] = f2bf(lds[c * 129 + w]);
    }
}

// ---- Kernel 2: weight -> MFMA B-fragment order (bf16) ----
__global__ __launch_bounds__(256) void k_weight(const float* __restrict__ w,
                                                unsigned short* __restrict__ wtf) {
    int t = blockIdx.x * 256 + threadIdx.x;
    if (t >= 18 * 4 * 64 * 8) return;
    int j    = t & 7;
    int lane = (t >> 3) & 63;
    int nt   = (t >> 9) & 3;
    int s    = t >> 11;
    int kg   = s * 32 + ((lane >> 4) << 3) + j;
    int n    = nt * 16 + (lane & 15);
    int kpos = kg >> 6, c = kg & 63;
    wtf[t] = f2bf(w[(n * CIN + c) * 9 + kpos]);
}

// ---- Main: 8x16 px tile, 8 waves (wave = row); asm-pinned B prefetch ----
__global__ __launch_bounds__(512, 4) void k_main(
    const unsigned short* __restrict__ xt,
    const float* __restrict__ offset,
    const float* __restrict__ mask,
    const unsigned short* __restrict__ wtf,
    const float* __restrict__ bias,
    float* __restrict__ out) {
    __shared__ __align__(16) unsigned char smem[SMEMB];   // 52 KB

    const int tid  = threadIdx.x;
    const int lane = tid & 63;
    const int wv   = tid >> 6;          // 0..7 = pixel row within tile
    const int T  = ((blockIdx.x & 7) << 6) + (blockIdx.x >> 3);
    const int b  = T >> 7;
    const int i0 = ((T >> 3) & 15) * 8;
    const int j0 = (T & 7) * 16;
    const char* xb = (const char*)xt + (size_t)b * HW * 128;
    const char* bbase = (const char*)wtf + (size_t)lane * 16;

    // prologue: issue B(0) immediately — staging covers its latency
    bf16x8 bA0, bA1, bA2, bA3, bB0, bB1, bB2, bB3;
    // NOTE "=&v" early-clobber: outputs must NOT alias the address pair %4
#define ISSUE_B(S, B0, B1, B2, B3) do { \
    const char* _ba = bbase + (S) * 4096; \
    asm volatile( \
        "global_load_dwordx4 %0, %4, off\n\t" \
        "global_load_dwordx4 %1, %4, off offset:1024\n\t" \
        "global_load_dwordx4 %2, %4, off offset:2048\n\t" \
        "global_load_dwordx4 %3, %4, off offset:3072" \
        : "=&v"(B0), "=&v"(B1), "=&v"(B2), "=&v"(B3) \
        : "v"(_ba) : "memory"); \
} while (0)
    ISSUE_B(0, bA0, bA1, bA2, bA3);

    // -------- stage 14x22 record region (halo 3), chunk-rotation swizzle ----
    {
        const int iA = i0 - HALO, jA = j0 - HALO;
#pragma unroll
        for (int k = 0; k < 5; ++k) {
            int idx = k * 512 + tid;          // 2464 chunks
            if (idx < RECS * 8) {
                int rec = idx >> 3, c = idx & 7;
                int rr = rec / COLS_R, cc = rec - rr * COLS_R;
                int gr = min(max(iA + rr, 0), H_ - 1);
                int gc = min(max(jA + cc, 0), W_ - 1);
                u32x4 v = *(const u32x4*)(xb + (((gr << 7) + gc) << 7) + (c << 4));
                *(u32x4*)(smem + (rec << 7) + (((c + rec) & 7) << 4)) = v;
            }
        }
    }
    // -------- stage offset+mask planes [27][8][16] f32 --------
    {
        const float* op = offset + (size_t)b * 18 * HW;
        const float* mp = mask   + (size_t)b * 9  * HW;
#pragma unroll
        for (int k = 0; k < 2; ++k) {
            int idx = k * 512 + tid;          // 864 f32x4 chunks
            if (idx < 864) {
                int q = idx >> 5, rem = idx & 31;
                int row = rem >> 2, c4 = (rem & 3) << 2;
                const float* src = (q < 18 ? op + q * HW : mp + (q - 18) * HW)
                                   + (i0 + row) * W_ + j0 + c4;
                *(f32x4*)(smem + OFFB + idx * 16) = *(const f32x4*)src;
            }
        }
    }
    __syncthreads();

    const int p  = lane & 15;            // px col within row
    const int g  = lane >> 4;            // channel group
    const int ir = i0 + wv;
    const int jc = j0 + p;
    // preload this lane's 27 offset/mask scalars to registers (one LDS wait)
    const float* offl = (const float*)(smem + OFFB) + wv * 16 + p;
    float offv[18], mskv[9];
#pragma unroll
    for (int q = 0; q < 18; ++q) offv[q] = offl[q * 128];
#pragma unroll
    for (int q = 0; q < 9; ++q)  mskv[q] = offl[(18 + q) * 128];

    f32x4 acc0 = {0,0,0,0}, acc1 = {0,0,0,0}, acc2 = {0,0,0,0}, acc3 = {0,0,0,0};

#define BLEND(AF) do { \
    u32x4 po; \
    _Pragma("unroll") \
    for (int q = 0; q < 4; ++q) { \
        f32x2 c00 = {__uint_as_float(q00[q] << 16), __uint_as_float(q00[q] & 0xFFFF0000u)}; \
        f32x2 c01 = {__uint_as_float(q01[q] << 16), __uint_as_float(q01[q] & 0xFFFF0000u)}; \
        f32x2 c10 = {__uint_as_float(q10[q] << 16), __uint_as_float(q10[q] & 0xFFFF0000u)}; \
        f32x2 c11 = {__uint_as_float(q11[q] << 16), __uint_as_float(q11[q] & 0xFFFF0000u)}; \
        f32x2 r = wx * c00 + wy * c01 + wz * c10 + ww * c11; \
        po[q] = __builtin_amdgcn_perm(__float_as_uint(r.y) + 0x8000u, \
                                      __float_as_uint(r.x) + 0x8000u, 0x07060302u); \
    } \
    *(u32x4*)&(AF) = po; } while (0)

#define CORNERS(H) \
    int ch = (H) * 4 + g; \
    u32x4 q00 = *(const u32x4*)(smem + (r00 << 7) + (((ch + r00) & 7) << 4)); \
    u32x4 q01 = *(const u32x4*)(smem + (r01 << 7) + (((ch + r01) & 7) << 4)); \
    u32x4 q10 = *(const u32x4*)(smem + (r10 << 7) + (((ch + r10) & 7) << 4)); \
    u32x4 q11 = *(const u32x4*)(smem + (r11 << 7) + (((ch + r11) & 7) << 4)); \
    if (!inr) { \
        int c = (g << 4) + ((H) << 6); \
        q00 = *(const u32x4*)(xb + a00 + c); \
        q01 = *(const u32x4*)(xb + a01 + c); \
        q10 = *(const u32x4*)(xb + a10 + c); \
        q11 = *(const u32x4*)(xb + a11 + c); \
    }

#define WAIT_MFMA(AF, B0, B1, B2, B3) do { \
    asm volatile("s_waitcnt vmcnt(0)" ::: "memory"); \
    __builtin_amdgcn_sched_barrier(0); \
    acc0 = __builtin_amdgcn_mfma_f32_16x16x32_bf16(AF, B0, acc0, 0, 0, 0); \
    acc1 = __builtin_amdgcn_mfma_f32_16x16x32_bf16(AF, B1, acc1, 0, 0, 0); \
    acc2 = __builtin_amdgcn_mfma_f32_16x16x32_bf16(AF, B2, acc2, 0, 0, 0); \
    acc3 = __builtin_amdgcn_mfma_f32_16x16x32_bf16(AF, B3, acc3, 0, 0, 0); } while (0)

#pragma unroll
    for (int kp = 0; kp < 9; ++kp) {
        // ---- meta for this kp (all values in registers) ----
        float oi  = offv[2 * kp];
        float oj  = offv[2 * kp + 1];
        float msk = mskv[kp];
        float ci = oi + (float)(ir + kp / 3 - 1);
        float cj = oj + (float)(jc + kp % 3 - 1);
        float fli = floorf(ci), flj = floorf(cj);
        float fi = ci - fli, fj = cj - flj;
        int li = (int)fli, lj = (int)flj;
        int rli = li - (i0 - HALO), rlj = lj - (j0 - HALO);
        bool inr = ((unsigned)rli <= (unsigned)(ROWS_R - 2)) &&
                   ((unsigned)rlj <= (unsigned)(COLS_R - 2));
        float vy0 = (li   >= 0 && li   < H_) ? 1.f : 0.f;
        float vy1 = (li+1 >= 0 && li+1 < H_) ? 1.f : 0.f;
        float vx0 = (lj   >= 0 && lj   < W_) ? 1.f : 0.f;
        float vx1 = (lj+1 >= 0 && lj+1 < W_) ? 1.f : 0.f;
        float gi = fi * msk, gj = fj * msk;
        float w11 = gi * fj;
        float w4x = (msk - gi - gj + w11) * vy0 * vx0;
        float w4y = (gj - w11) * vy0 * vx1;
        float w4z = (gi - w11) * vy1 * vx0;
        float w4w = w11 * vy1 * vx1;
        f32x2 wx = {w4x, w4x}, wy = {w4y, w4y}, wz = {w4z, w4z}, ww = {w4w, w4w};
        int y0 = min(max(li,   0), H_ - 1), y1 = min(max(li+1, 0), H_ - 1);
        int x0 = min(max(lj,   0), W_ - 1), x1 = min(max(lj+1, 0), W_ - 1);
        int a00 = ((y0 << 7) + x0) << 7, a01 = ((y0 << 7) + x1) << 7;
        int a10 = ((y1 << 7) + x0) << 7, a11 = ((y1 << 7) + x1) << 7;
        int rli_c = min(max(rli, 0), ROWS_R - 2), rlj_c = min(max(rlj, 0), COLS_R - 2);
        int r00 = rli_c * COLS_R + rlj_c;
        int r01 = r00 + 1, r10 = r00 + COLS_R, r11 = r00 + COLS_R + 1;

        // ---- h = 0: s = 2kp (even, consume bufA); prefetch s+1 into bufB ----
        {
            ISSUE_B(2 * kp + 1, bB0, bB1, bB2, bB3);
            CORNERS(0);
            bf16x8 af;
            BLEND(af);
            WAIT_MFMA(af, bA0, bA1, bA2, bA3);
        }
        // ---- h = 1: s = 2kp+1 (odd, consume bufB); prefetch s+1 into bufA ----
        {
            if (kp < 8) ISSUE_B(2 * kp + 2, bA0, bA1, bA2, bA3);
            CORNERS(1);
            bf16x8 af;
            BLEND(af);
            WAIT_MFMA(af, bB0, bB1, bB2, bB3);
        }
    }

    // -------- epilogue: reuse smem as cst[64][132] f32, full-line writes ----
    __syncthreads();
    float* cst = (float*)smem;
    {
        f32x4 v0 = acc0, v1 = acc1, v2 = acc2, v3 = acc3;
        float bs0 = bias[p], bs1 = bias[16 + p], bs2 = bias[32 + p], bs3 = bias[48 + p];
#pragma unroll
        for (int r = 0; r < 4; ++r) { v0[r] += bs0; v1[r] += bs1; v2[r] += bs2; v3[r] += bs3; }
        const int pm = wv * 16 + (g << 2);   // pixel-local base for lane's 4 m-rows
        *(f32x4*)&cst[(p)      * 132 + pm] = v0;
        *(f32x4*)&cst[(16 + p) * 132 + pm] = v1;
        *(f32x4*)&cst[(32 + p) * 132 + pm] = v2;
        *(f32x4*)&cst[(48 + p) * 132 + pm] = v3;
    }
    __syncthreads();
    const size_t obase = (size_t)b * (COUT * HW) + i0 * W_ + j0;
#pragma unroll
    for (int k = 0; k < 4; ++k) {
        int idx = k * 512 + tid;            // 2048 f32x4 chunks
        int cout = idx >> 5, chunk = idx & 31;
        int row = chunk >> 2, col = (chunk & 3) << 2;
        f32x4 vv = *(const f32x4*)&cst[cout * 132 + chunk * 4];
        __builtin_nontemporal_store(vv,
            (f32x4*)&out[obase + (size_t)cout * HW + row * W_ + col]);
    }
}

extern "C" void kernel_launch(void* const* d_in, const int* in_sizes, int n_in,
                              void* d_out, int out_size, void* d_ws, size_t ws_size,
                              hipStream_t stream) {
    const float* x      = (const float*)d_in[0];
    const float* offset = (const float*)d_in[1];
    const float* mask   = (const float*)d_in[2];
    const float* weight = (const float*)d_in[3];
    const float* bias   = (const float*)d_in[4];
    float* out = (float*)d_out;
    char* ws = (char*)d_ws;
    unsigned short* xt  = (unsigned short*)ws;                        // 8 MB
    unsigned short* wtf = (unsigned short*)(ws + 8388608);            // 72 KB

    k_transpose<<<B_ * H_, 256, 0, stream>>>(x, xt);
    k_weight<<<144, 256, 0, stream>>>(weight, wtf);
    k_main<<<NBLK, 512, 0, stream>>>(xt, offset, mask, wtf, bias, out);
}